// Round 23
// baseline (106.215 us; speedup 1.0000x reference)
//
#include <hip/hip_runtime.h>

#define ROWS 8192
#define KDIM 4096
#define NDIM 4096

typedef float f32x4 __attribute__((ext_vector_type(4)));

// ws layout (floats):
//   w01 : [4096][16]  at 0      (65536)   -- k-major, r2 contiguous
//   w23 : [16][4096]  at 65536  (65536)
//
// R23: R21 staging (best, 55.96us) + ONE lever: 16 rows per WAVE (was 8).
// Each wave reads its full w01 k-segment regardless of rows, so w-traffic
// per output row halves (grid total 256 MB -> 128 MB of L1/L2 return).
// Block = 512 thr / 8 waves; wave wv: k-seg wv*512, all 16 block rows,
// 4 chunks of 128 k via wave-private LDS (R21's plain coalesced staging).
// Butterfly = R5 scatter extended one level (lane ends with 2 rows,
// bit-2 selects the write; static indices only). Phase 2 = R18's 16-row
// j-sweep. Grid 512 = 2 blocks/CU (16 waves/CU, same as R21).

__device__ inline f32x4 fma4(float s, f32x4 w, f32x4 a) {
    a.x = fmaf(s, w.x, a.x);
    a.y = fmaf(s, w.y, a.y);
    a.z = fmaf(s, w.z, a.z);
    a.w = fmaf(s, w.w, a.w);
    return a;
}
__device__ inline f32x4 shfl_xor4(f32x4 v, int m) {
    v.x = __shfl_xor(v.x, m, 64);
    v.y = __shfl_xor(v.y, m, 64);
    v.z = __shfl_xor(v.z, m, 64);
    v.w = __shfl_xor(v.w, m, 64);
    return v;
}

// ---------------------------------------------------------------------------
// Build W01 (4096x16, k-major) and W23 (16x4096) from the TT cores.
// ---------------------------------------------------------------------------
__global__ __launch_bounds__(256) void tt_prep(
    const float* __restrict__ c0, const float* __restrict__ c1,
    const float* __restrict__ c2, const float* __restrict__ c3,
    float* __restrict__ w01, float* __restrict__ w23)
{
    int gid = blockIdx.x * 256 + threadIdx.x;  // 0..131071
    if (gid < 65536) {
        int p = gid >> 4, r2 = gid & 15;
        int n0 = p >> 6, n1 = p & 63;
        float s = 0.f;
        #pragma unroll
        for (int r1 = 0; r1 < 16; ++r1)
            s = fmaf(c0[n0 * 16 + r1], c1[(r1 * 64 + n1) * 16 + r2], s);
        w01[gid] = s;
    } else {
        int g = gid - 65536;
        int r2 = g >> 12, j = g & 4095;
        int n2 = j >> 6, n3 = j & 63;
        float s = 0.f;
        #pragma unroll
        for (int r3 = 0; r3 < 16; ++r3)
            s = fmaf(c2[(r2 * 64 + n2) * 16 + r3], c3[r3 * 64 + n3], s);
        w23[g] = s;
    }
}

// ---------------------------------------------------------------------------
// Fused: out[16 rows] = (x[16 rows] @ W01) @ W23 per block.
// Grid 512 x 512 thr.
// ---------------------------------------------------------------------------
__global__ __launch_bounds__(512, 4) void tt_fused(
    const float* __restrict__ x, const float* __restrict__ w01,
    const float* __restrict__ w23, float* __restrict__ out)
{
    __shared__ __align__(16) float ldsx[8][16][128]; // 64 KB wave-private chunks
    __shared__ __align__(16) float tsp[8][16][16];   // 8 KB per-wave partial T
    __shared__ __align__(16) float ts[16][16];       // summed T tile
    const int t = threadIdx.x;
    const int lane = t & 63;
    const int wv = t >> 6;            // wave 0..7: K segment owner
    const int q = lane & 3;           // r2 quad
    const int klane = lane >> 2;      // 0..15
    const int row0 = blockIdx.x * 16;
    const int k0 = wv * 512;
    const int rh = lane >> 5;         // row-half for staging (0/1)
    const int cl = (lane & 31) * 4;   // staging column

    const float* xb = x + (size_t)row0 * KDIM + k0;
    const float* wb = w01 + (size_t)k0 * 16;

    // ---- Phase 1: LDS-staged broadcast engine; 4 chunks of 128 k.
    f32x4 acc[16];
    #pragma unroll
    for (int r = 0; r < 16; ++r) acc[r] = (f32x4)(0.f);

    #pragma unroll 1
    for (int ch = 0; ch < 4; ++ch) {
        // Stage: 16 rows x 128 k; 8 plain coalesced loads (2x512 B each).
        f32x4 xs[8];
        #pragma unroll
        for (int i = 0; i < 8; ++i)
            xs[i] = *(const f32x4*)&xb[(size_t)(2 * i + rh) * KDIM + ch * 128 + cl];
        #pragma unroll
        for (int i = 0; i < 8; ++i)
            *(f32x4*)&ldsx[wv][2 * i + rh][cl] = xs[i];

        // Compute: 2 x 64-k iterations; x from LDS broadcast.
        #pragma unroll
        for (int it = 0; it < 2; ++it) {
            const int kk0 = it * 64 + klane * 4;
            f32x4 wq[4];
            #pragma unroll
            for (int kk = 0; kk < 4; ++kk)
                wq[kk] = *(const f32x4*)&wb[(size_t)(ch * 128 + kk0 + kk) * 16 + q * 4];
            #pragma unroll
            for (int r = 0; r < 16; ++r) {
                f32x4 xv = *(const f32x4*)&ldsx[wv][r][kk0];
                #pragma unroll
                for (int kk = 0; kk < 4; ++kk)
                    acc[r] = fma4(xv[kk], wq[kk], acc[r]);
            }
        }
    }

    // Reduce-scatter butterfly over klane, R5 keep-upper convention,
    // extended to 16 rows: after b5,b4,b3 scatter each lane holds 2 rows;
    // plain stage bit 2 completes the klane sum; bit-2 selects the row.
    const bool b5 = lane & 32, b4 = lane & 16, b3 = lane & 8;
    f32x4 s1[8];
    #pragma unroll
    for (int j = 0; j < 8; ++j) {
        f32x4 send = b5 ? acc[j] : acc[8 + j];
        f32x4 keep = b5 ? acc[8 + j] : acc[j];
        s1[j] = keep + shfl_xor4(send, 32);
    }
    f32x4 s2[4];
    #pragma unroll
    for (int j = 0; j < 4; ++j) {
        f32x4 send = b4 ? s1[j] : s1[4 + j];
        f32x4 keep = b4 ? s1[4 + j] : s1[j];
        s2[j] = keep + shfl_xor4(send, 16);
    }
    f32x4 s3[2];
    #pragma unroll
    for (int j = 0; j < 2; ++j) {
        f32x4 send = b3 ? s2[j] : s2[2 + j];
        f32x4 keep = b3 ? s2[2 + j] : s2[j];
        s3[j] = keep + shfl_xor4(send, 8);
    }
    s3[0] += shfl_xor4(s3[0], 4);
    s3[1] += shfl_xor4(s3[1], 4);

    {
        f32x4 v = (lane & 4) ? s3[1] : s3[0];
        int row = ((lane >> 5) & 1) * 8 + ((lane >> 4) & 1) * 4
                + ((lane >> 3) & 1) * 2 + ((lane >> 2) & 1);
        *(f32x4*)&tsp[wv][row][q * 4] = v;
    }
    __syncthreads();

    // Sum the 8 wave partials into ts[16][16].
    if (t < 256) {
        int row = t >> 4, r = t & 15;
        float s = 0.f;
        #pragma unroll
        for (int w8 = 0; w8 < 8; ++w8)
            s += tsp[w8][row][r];
        ts[row][r] = s;
    }
    __syncthreads();

    // ---- Phase 2 (R18-verified): 2 j-tiles of 2048; w[16] over 16 rows.
    const size_t obase = (size_t)row0 * NDIM;
    #pragma unroll 1
    for (int jt = 0; jt < 2; ++jt) {
        const int j0 = jt * 2048 + t * 4;
        f32x4 w[16];
        #pragma unroll
        for (int r = 0; r < 16; ++r)
            w[r] = *(const f32x4*)&w23[r * NDIM + j0];
        #pragma unroll 2
        for (int row = 0; row < 16; ++row) {
            const f32x4* trp = (const f32x4*)&ts[row][0];
            f32x4 t0 = trp[0], t1 = trp[1], t2 = trp[2], t3 = trp[3];
            f32x4 a = (f32x4)(0.f);
            a = fma4(t0.x, w[0],  a); a = fma4(t0.y, w[1],  a);
            a = fma4(t0.z, w[2],  a); a = fma4(t0.w, w[3],  a);
            a = fma4(t1.x, w[4],  a); a = fma4(t1.y, w[5],  a);
            a = fma4(t1.z, w[6],  a); a = fma4(t1.w, w[7],  a);
            a = fma4(t2.x, w[8],  a); a = fma4(t2.y, w[9],  a);
            a = fma4(t2.z, w[10], a); a = fma4(t2.w, w[11], a);
            a = fma4(t3.x, w[12], a); a = fma4(t3.y, w[13], a);
            a = fma4(t3.z, w[14], a); a = fma4(t3.w, w[15], a);
            __builtin_nontemporal_store(a,
                (f32x4*)&out[obase + (size_t)row * NDIM + j0]);
        }
    }
}

extern "C" void kernel_launch(void* const* d_in, const int* in_sizes, int n_in,
                              void* d_out, int out_size, void* d_ws, size_t ws_size,
                              hipStream_t stream) {
    const float* x  = (const float*)d_in[0];
    const float* c0 = (const float*)d_in[1];
    const float* c1 = (const float*)d_in[2];
    const float* c2 = (const float*)d_in[3];
    const float* c3 = (const float*)d_in[4];
    float* out = (float*)d_out;

    float* w01 = (float*)d_ws;
    float* w23 = w01 + 65536;

    tt_prep<<<512, 256, 0, stream>>>(c0, c1, c2, c3, w01, w23);
    tt_fused<<<512, 512, 0, stream>>>(x, w01, w23, out);
}

// Round 24
// 56.224 us; speedup vs baseline: 1.8891x; 1.8891x over previous
//
#include <hip/hip_runtime.h>

#define ROWS 8192
#define KDIM 4096
#define NDIM 4096

typedef float f32x4 __attribute__((ext_vector_type(4)));

// ws layout (floats):
//   w01 : [4096][16]  at 0      (65536)   -- k-major, r2 contiguous
//   w23 : [16][4096]  at 65536  (65536)
//
// R24 = byte-exact revert to R21 (verified best, 55.96 us).
// Fused kernel: phase 1 = LDS-staged broadcast engine (plain coalesced
// staging loads -> wave-private LDS; 4-lane broadcast reads from LDS are
// free), R5-verified butterfly reduce; phase 2 = j-sweep with w[16] in
// regs and NT out-stores. Grid 1024 = 4 blocks/CU.

__device__ inline f32x4 fma4(float s, f32x4 w, f32x4 a) {
    a.x = fmaf(s, w.x, a.x);
    a.y = fmaf(s, w.y, a.y);
    a.z = fmaf(s, w.z, a.z);
    a.w = fmaf(s, w.w, a.w);
    return a;
}
__device__ inline f32x4 shfl_xor4(f32x4 v, int m) {
    v.x = __shfl_xor(v.x, m, 64);
    v.y = __shfl_xor(v.y, m, 64);
    v.z = __shfl_xor(v.z, m, 64);
    v.w = __shfl_xor(v.w, m, 64);
    return v;
}

// ---------------------------------------------------------------------------
// Build W01 (4096x16, k-major) and W23 (16x4096) from the TT cores.
// ---------------------------------------------------------------------------
__global__ __launch_bounds__(256) void tt_prep(
    const float* __restrict__ c0, const float* __restrict__ c1,
    const float* __restrict__ c2, const float* __restrict__ c3,
    float* __restrict__ w01, float* __restrict__ w23)
{
    int gid = blockIdx.x * 256 + threadIdx.x;  // 0..131071
    if (gid < 65536) {
        int p = gid >> 4, r2 = gid & 15;
        int n0 = p >> 6, n1 = p & 63;
        float s = 0.f;
        #pragma unroll
        for (int r1 = 0; r1 < 16; ++r1)
            s = fmaf(c0[n0 * 16 + r1], c1[(r1 * 64 + n1) * 16 + r2], s);
        w01[gid] = s;
    } else {
        int g = gid - 65536;
        int r2 = g >> 12, j = g & 4095;
        int n2 = j >> 6, n3 = j & 63;
        float s = 0.f;
        #pragma unroll
        for (int r3 = 0; r3 < 16; ++r3)
            s = fmaf(c2[(r2 * 64 + n2) * 16 + r3], c3[r3 * 64 + n3], s);
        w23[g] = s;
    }
}

// ---------------------------------------------------------------------------
// Fused: out[8 rows] = (x[8 rows] @ W01) @ W23 per block. Grid 1024.
// ---------------------------------------------------------------------------
__global__ __launch_bounds__(256) void tt_fused(
    const float* __restrict__ x, const float* __restrict__ w01,
    const float* __restrict__ w23, float* __restrict__ out)
{
    __shared__ __align__(16) float ldsx[4][8][256]; // 32 KB, wave-private chunks
    __shared__ __align__(16) float tsp[4][8][16];   // per-wave partial T
    __shared__ __align__(16) float ts[8][16];       // summed T tile
    const int t = threadIdx.x;
    const int lane = t & 63;
    const int wv = t >> 6;            // wave 0..3: K segment owner
    const int q = lane & 3;           // r2 quad
    const int klane = lane >> 2;      // 0..15
    const int row0 = blockIdx.x * 8;
    const int k0 = wv * 1024;

    const float* xb = x + (size_t)row0 * KDIM + k0;
    const float* wb = w01 + (size_t)k0 * 16;

    // ---- Phase 1: LDS-staged broadcast engine. 4 chunks of 256 k.
    f32x4 acc[8];
    #pragma unroll
    for (int r = 0; r < 8; ++r) acc[r] = (f32x4)(0.f);

    #pragma unroll 1
    for (int ch = 0; ch < 4; ++ch) {
        // Stage: 8 rows x 256 k, plain fully-coalesced loads (1 KB unique
        // per instruction), then ds_write. Wave-private region: no barrier;
        // compiler inserts the lgkmcnt/vmcnt waits for the RAW/WAR hazards.
        f32x4 xs[8];
        #pragma unroll
        for (int r = 0; r < 8; ++r)
            xs[r] = *(const f32x4*)&xb[(size_t)r * KDIM + ch * 256 + lane * 4];
        #pragma unroll
        for (int r = 0; r < 8; ++r)
            *(f32x4*)&ldsx[wv][r][lane * 4] = xs[r];

        // Compute: 4 x 64-k iterations; x from LDS (4-lane same-address
        // broadcast is free), w from L1/L2 (R5-verified mapping).
        #pragma unroll 2
        for (int it = 0; it < 4; ++it) {
            const int kk0 = it * 64 + klane * 4;
            f32x4 wq[4];
            #pragma unroll
            for (int kk = 0; kk < 4; ++kk)
                wq[kk] = *(const f32x4*)&wb[(size_t)(ch * 256 + kk0 + kk) * 16 + q * 4];
            f32x4 xv[8];
            #pragma unroll
            for (int r = 0; r < 8; ++r)
                xv[r] = *(const f32x4*)&ldsx[wv][r][kk0];
            #pragma unroll
            for (int kk = 0; kk < 4; ++kk)
                #pragma unroll
                for (int r = 0; r < 8; ++r)
                    acc[r] = fma4(xv[r][kk], wq[kk], acc[r]);
        }
    }

    // R5-verified reduce-scatter butterfly over klane (static indices only).
    const bool b5 = lane & 32, b4 = lane & 16, b3 = lane & 8;
    f32x4 s1[4];
    #pragma unroll
    for (int j = 0; j < 4; ++j) {
        f32x4 send = b5 ? acc[j] : acc[4 + j];
        f32x4 keep = b5 ? acc[4 + j] : acc[j];
        s1[j] = keep + shfl_xor4(send, 32);
    }
    f32x4 s2[2];
    #pragma unroll
    for (int j = 0; j < 2; ++j) {
        f32x4 send = b4 ? s1[j] : s1[2 + j];
        f32x4 keep = b4 ? s1[2 + j] : s1[j];
        s2[j] = keep + shfl_xor4(send, 16);
    }
    f32x4 s3;
    {
        f32x4 send = b3 ? s2[0] : s2[1];
        f32x4 keep = b3 ? s2[1] : s2[0];
        s3 = keep + shfl_xor4(send, 8);
    }
    s3 += shfl_xor4(s3, 4);

    if ((lane & 4) == 0) {
        int row = (lane >> 3) & 7;
        *(f32x4*)&tsp[wv][row][q * 4] = s3;
    }
    __syncthreads();

    // Sum the 4 wave partials into ts[8][16].
    if (t < 128) {
        int row = t >> 4, r = t & 15;
        ts[row][r] = tsp[0][row][r] + tsp[1][row][r]
                   + tsp[2][row][r] + tsp[3][row][r];
    }
    __syncthreads();

    // ---- Phase 2: R5-verified j-sweep. 4 j-tiles of 1024; w[16] in regs.
    const size_t obase = (size_t)row0 * NDIM;
    #pragma unroll 1
    for (int jt = 0; jt < 4; ++jt) {
        const int j0 = jt * 1024 + t * 4;
        f32x4 w[16];
        #pragma unroll
        for (int r = 0; r < 16; ++r)
            w[r] = *(const f32x4*)&w23[r * NDIM + j0];
        #pragma unroll 2
        for (int row = 0; row < 8; ++row) {
            const f32x4* trp = (const f32x4*)&ts[row][0];
            f32x4 t0 = trp[0], t1 = trp[1], t2 = trp[2], t3 = trp[3];
            f32x4 a = (f32x4)(0.f);
            a = fma4(t0.x, w[0],  a); a = fma4(t0.y, w[1],  a);
            a = fma4(t0.z, w[2],  a); a = fma4(t0.w, w[3],  a);
            a = fma4(t1.x, w[4],  a); a = fma4(t1.y, w[5],  a);
            a = fma4(t1.z, w[6],  a); a = fma4(t1.w, w[7],  a);
            a = fma4(t2.x, w[8],  a); a = fma4(t2.y, w[9],  a);
            a = fma4(t2.z, w[10], a); a = fma4(t2.w, w[11], a);
            a = fma4(t3.x, w[12], a); a = fma4(t3.y, w[13], a);
            a = fma4(t3.z, w[14], a); a = fma4(t3.w, w[15], a);
            __builtin_nontemporal_store(a,
                (f32x4*)&out[obase + (size_t)row * NDIM + j0]);
        }
    }
}

extern "C" void kernel_launch(void* const* d_in, const int* in_sizes, int n_in,
                              void* d_out, int out_size, void* d_ws, size_t ws_size,
                              hipStream_t stream) {
    const float* x  = (const float*)d_in[0];
    const float* c0 = (const float*)d_in[1];
    const float* c1 = (const float*)d_in[2];
    const float* c2 = (const float*)d_in[3];
    const float* c3 = (const float*)d_in[4];
    float* out = (float*)d_out;

    float* w01 = (float*)d_ws;
    float* w23 = w01 + 65536;

    tt_prep<<<512, 256, 0, stream>>>(c0, c1, c2, c3, w01, w23);
    tt_fused<<<1024, 256, 0, stream>>>(x, w01, w23, out);
}

// Round 25
// 54.640 us; speedup vs baseline: 1.9439x; 1.0290x over previous
//
#include <hip/hip_runtime.h>

#define ROWS 8192
#define KDIM 4096
#define NDIM 4096

typedef float f32x4 __attribute__((ext_vector_type(4)));

// ws layout (floats):
//   w01 : [4096][16]  at 0      (65536)   -- k-major, r2 contiguous
//   w23 : [16][4096]  at 65536  (65536)
//
// R25: R21/R24 (best, 56.0us) + ONE variable: staging chunk 256 -> 128 k.
// ldsx 32 KB -> 16 KB => block LDS ~19 KB => 8 blocks/CU = 32 waves/CU
// (was 4 blocks / 16 waves, LDS-capped). Tests whether phase-1's ~50%
// residual stall is hideable with 2x wave parallelism. Staging stays
// 1 KB-unique per instruction (two 512 B row segments).

__device__ inline f32x4 fma4(float s, f32x4 w, f32x4 a) {
    a.x = fmaf(s, w.x, a.x);
    a.y = fmaf(s, w.y, a.y);
    a.z = fmaf(s, w.z, a.z);
    a.w = fmaf(s, w.w, a.w);
    return a;
}
__device__ inline f32x4 shfl_xor4(f32x4 v, int m) {
    v.x = __shfl_xor(v.x, m, 64);
    v.y = __shfl_xor(v.y, m, 64);
    v.z = __shfl_xor(v.z, m, 64);
    v.w = __shfl_xor(v.w, m, 64);
    return v;
}

// ---------------------------------------------------------------------------
// Build W01 (4096x16, k-major) and W23 (16x4096) from the TT cores.
// ---------------------------------------------------------------------------
__global__ __launch_bounds__(256) void tt_prep(
    const float* __restrict__ c0, const float* __restrict__ c1,
    const float* __restrict__ c2, const float* __restrict__ c3,
    float* __restrict__ w01, float* __restrict__ w23)
{
    int gid = blockIdx.x * 256 + threadIdx.x;  // 0..131071
    if (gid < 65536) {
        int p = gid >> 4, r2 = gid & 15;
        int n0 = p >> 6, n1 = p & 63;
        float s = 0.f;
        #pragma unroll
        for (int r1 = 0; r1 < 16; ++r1)
            s = fmaf(c0[n0 * 16 + r1], c1[(r1 * 64 + n1) * 16 + r2], s);
        w01[gid] = s;
    } else {
        int g = gid - 65536;
        int r2 = g >> 12, j = g & 4095;
        int n2 = j >> 6, n3 = j & 63;
        float s = 0.f;
        #pragma unroll
        for (int r3 = 0; r3 < 16; ++r3)
            s = fmaf(c2[(r2 * 64 + n2) * 16 + r3], c3[r3 * 64 + n3], s);
        w23[g] = s;
    }
}

// ---------------------------------------------------------------------------
// Fused: out[8 rows] = (x[8 rows] @ W01) @ W23 per block. Grid 1024.
// ---------------------------------------------------------------------------
__global__ __launch_bounds__(256) void tt_fused(
    const float* __restrict__ x, const float* __restrict__ w01,
    const float* __restrict__ w23, float* __restrict__ out)
{
    __shared__ __align__(16) float ldsx[4][8][128]; // 16 KB, wave-private chunks
    __shared__ __align__(16) float tsp[4][8][16];   // per-wave partial T
    __shared__ __align__(16) float ts[8][16];       // summed T tile
    const int t = threadIdx.x;
    const int lane = t & 63;
    const int wv = t >> 6;            // wave 0..3: K segment owner
    const int q = lane & 3;           // r2 quad
    const int klane = lane >> 2;      // 0..15
    const int rh = lane >> 5;         // staging row parity (0/1)
    const int cl = (lane & 31) * 4;   // staging column 0..124
    const int row0 = blockIdx.x * 8;
    const int k0 = wv * 1024;

    const float* xb = x + (size_t)row0 * KDIM + k0;
    const float* wb = w01 + (size_t)k0 * 16;

    // ---- Phase 1: LDS-staged broadcast engine. 8 chunks of 128 k.
    f32x4 acc[8];
    #pragma unroll
    for (int r = 0; r < 8; ++r) acc[r] = (f32x4)(0.f);

    #pragma unroll 1
    for (int ch = 0; ch < 8; ++ch) {
        // Stage: 8 rows x 128 k; 4 loads, each two 512 B row segments
        // (1 KB unique per instruction). Wave-private: no barrier.
        f32x4 xs[4];
        #pragma unroll
        for (int i = 0; i < 4; ++i)
            xs[i] = *(const f32x4*)&xb[(size_t)(2 * i + rh) * KDIM + ch * 128 + cl];
        #pragma unroll
        for (int i = 0; i < 4; ++i)
            *(f32x4*)&ldsx[wv][2 * i + rh][cl] = xs[i];

        // Compute: 2 x 64-k iterations; x from LDS broadcast (free),
        // w from L1/L2 (R5-verified mapping).
        #pragma unroll 2
        for (int it = 0; it < 2; ++it) {
            const int kk0 = it * 64 + klane * 4;
            f32x4 wq[4];
            #pragma unroll
            for (int kk = 0; kk < 4; ++kk)
                wq[kk] = *(const f32x4*)&wb[(size_t)(ch * 128 + kk0 + kk) * 16 + q * 4];
            f32x4 xv[8];
            #pragma unroll
            for (int r = 0; r < 8; ++r)
                xv[r] = *(const f32x4*)&ldsx[wv][r][kk0];
            #pragma unroll
            for (int kk = 0; kk < 4; ++kk)
                #pragma unroll
                for (int r = 0; r < 8; ++r)
                    acc[r] = fma4(xv[r][kk], wq[kk], acc[r]);
        }
    }

    // R5-verified reduce-scatter butterfly over klane (static indices only).
    const bool b5 = lane & 32, b4 = lane & 16, b3 = lane & 8;
    f32x4 s1[4];
    #pragma unroll
    for (int j = 0; j < 4; ++j) {
        f32x4 send = b5 ? acc[j] : acc[4 + j];
        f32x4 keep = b5 ? acc[4 + j] : acc[j];
        s1[j] = keep + shfl_xor4(send, 32);
    }
    f32x4 s2[2];
    #pragma unroll
    for (int j = 0; j < 2; ++j) {
        f32x4 send = b4 ? s1[j] : s1[2 + j];
        f32x4 keep = b4 ? s1[2 + j] : s1[j];
        s2[j] = keep + shfl_xor4(send, 16);
    }
    f32x4 s3;
    {
        f32x4 send = b3 ? s2[0] : s2[1];
        f32x4 keep = b3 ? s2[1] : s2[0];
        s3 = keep + shfl_xor4(send, 8);
    }
    s3 += shfl_xor4(s3, 4);

    if ((lane & 4) == 0) {
        int row = (lane >> 3) & 7;
        *(f32x4*)&tsp[wv][row][q * 4] = s3;
    }
    __syncthreads();

    // Sum the 4 wave partials into ts[8][16].
    if (t < 128) {
        int row = t >> 4, r = t & 15;
        ts[row][r] = tsp[0][row][r] + tsp[1][row][r]
                   + tsp[2][row][r] + tsp[3][row][r];
    }
    __syncthreads();

    // ---- Phase 2: R5-verified j-sweep. 4 j-tiles of 1024; w[16] in regs.
    const size_t obase = (size_t)row0 * NDIM;
    #pragma unroll 1
    for (int jt = 0; jt < 4; ++jt) {
        const int j0 = jt * 1024 + t * 4;
        f32x4 w[16];
        #pragma unroll
        for (int r = 0; r < 16; ++r)
            w[r] = *(const f32x4*)&w23[r * NDIM + j0];
        #pragma unroll 2
        for (int row = 0; row < 8; ++row) {
            const f32x4* trp = (const f32x4*)&ts[row][0];
            f32x4 t0 = trp[0], t1 = trp[1], t2 = trp[2], t3 = trp[3];
            f32x4 a = (f32x4)(0.f);
            a = fma4(t0.x, w[0],  a); a = fma4(t0.y, w[1],  a);
            a = fma4(t0.z, w[2],  a); a = fma4(t0.w, w[3],  a);
            a = fma4(t1.x, w[4],  a); a = fma4(t1.y, w[5],  a);
            a = fma4(t1.z, w[6],  a); a = fma4(t1.w, w[7],  a);
            a = fma4(t2.x, w[8],  a); a = fma4(t2.y, w[9],  a);
            a = fma4(t2.z, w[10], a); a = fma4(t2.w, w[11], a);
            a = fma4(t3.x, w[12], a); a = fma4(t3.y, w[13], a);
            a = fma4(t3.z, w[14], a); a = fma4(t3.w, w[15], a);
            __builtin_nontemporal_store(a,
                (f32x4*)&out[obase + (size_t)row * NDIM + j0]);
        }
    }
}

extern "C" void kernel_launch(void* const* d_in, const int* in_sizes, int n_in,
                              void* d_out, int out_size, void* d_ws, size_t ws_size,
                              hipStream_t stream) {
    const float* x  = (const float*)d_in[0];
    const float* c0 = (const float*)d_in[1];
    const float* c1 = (const float*)d_in[2];
    const float* c2 = (const float*)d_in[3];
    const float* c3 = (const float*)d_in[4];
    float* out = (float*)d_out;

    float* w01 = (float*)d_ws;
    float* w23 = w01 + 65536;

    tt_prep<<<512, 256, 0, stream>>>(c0, c1, c2, c3, w01, w23);
    tt_fused<<<1024, 256, 0, stream>>>(x, w01, w23, out);
}